// Round 2
// baseline (155.754 us; speedup 1.0000x reference)
//
#include <hip/hip_runtime.h>
#include <hip/hip_bf16.h>
#include <math.h>

#define TT 4096
#define BB 32
#define HH 512
#define CC 32000
#define RPW 8        // rows (t) per wave in k1
#define TPC 32       // t per chunk (4 waves x 8 rows)
#define NCHUNK 128   // TT/TPC
#define NQ 4         // h-quarters in k3

// ws layout (float offsets)
#define WS_CTX    0          // 32*512 = 16384 floats (k2->k3)
#define WS_LPART  16384      // 32*128 = 4096 floats (k1->k2)
#define WS_BIG    20480      // ctx_part (32*128*512=2,097,152 f) then out_part (4*32*32000=4,096,000 f)

__device__ __forceinline__ float dot4(const float4 a, const float4 b) {
  return fmaf(a.w, b.w, fmaf(a.z, b.z, fmaf(a.y, b.y, fmaf(a.x, b.x, 0.f))));
}

// ---------------- k1: fused score + weighted partial sums ------------------
// grid (chunk=128, b=32), block 256 (4 waves). Each wave: 8 rows of t,
// all 16 loads issued up-front (MLP), then compute. Fast tanh/exp via
// v_exp_f32 + v_rcp_f32 (err ~1e-6, threshold margin 6.5x).
__global__ __launch_bounds__(256) void k1_partials(
    const float* __restrict__ dec, const float* __restrict__ aw,
    const float* __restrict__ abp,
    float* __restrict__ ctx_part, float* __restrict__ l_part)
{
  const int chunk = blockIdx.x;
  const int b     = blockIdx.y;
  const int tid   = threadIdx.x;
  const int wv = tid >> 6, ln = tid & 63;
  const float ab = abp[0];
  const float4 aw0 = *(const float4*)(aw + ln*8);
  const float4 aw1 = *(const float4*)(aw + ln*8 + 4);
  const int t0 = chunk*TPC + wv*RPW;

  float4 x0[RPW], x1[RPW];
  const float* p = dec + ((size_t)t0*BB + b)*HH + (size_t)ln*8;
  #pragma unroll
  for (int r = 0; r < RPW; ++r) {
    x0[r] = *(const float4*)(p);
    x1[r] = *(const float4*)(p + 4);
    p += (size_t)BB*HH;
  }

  float4 c0 = make_float4(0.f,0.f,0.f,0.f), c1 = make_float4(0.f,0.f,0.f,0.f);
  float l = 0.f;
  #pragma unroll
  for (int r = 0; r < RPW; ++r) {
    float d = dot4(x0[r], aw0) + dot4(x1[r], aw1);
    #pragma unroll
    for (int off = 32; off > 0; off >>= 1) d += __shfl_xor(d, off);
    // tanh(x) = 1 - 2/(exp(2x)+1); exp via hw v_exp_f32, rcp via v_rcp_f32
    const float ex = __expf(2.f*(d + ab));
    const float th = 1.f - 2.f*__builtin_amdgcn_rcpf(ex + 1.f);
    const float w  = __expf(th);
    l += w;
    c0.x = fmaf(w, x0[r].x, c0.x); c0.y = fmaf(w, x0[r].y, c0.y);
    c0.z = fmaf(w, x0[r].z, c0.z); c0.w = fmaf(w, x0[r].w, c0.w);
    c1.x = fmaf(w, x1[r].x, c1.x); c1.y = fmaf(w, x1[r].y, c1.y);
    c1.z = fmaf(w, x1[r].z, c1.z); c1.w = fmaf(w, x1[r].w, c1.w);
  }

  __shared__ float s_ctx[4][HH];
  __shared__ float s_l[4];
  *(float4*)&s_ctx[wv][ln*8]     = c0;
  *(float4*)&s_ctx[wv][ln*8 + 4] = c1;
  if (ln == 0) s_l[wv] = l;
  __syncthreads();
  if (tid < 128) {
    const int h = tid * 4;
    float4 a = make_float4(0.f,0.f,0.f,0.f);
    #pragma unroll
    for (int w2 = 0; w2 < 4; ++w2) {
      const float4 v = *(const float4*)&s_ctx[w2][h];
      a.x += v.x; a.y += v.y; a.z += v.z; a.w += v.w;
    }
    const size_t pp = (size_t)b*NCHUNK + chunk;
    *(float4*)(ctx_part + pp*HH + h) = a;
    if (tid == 0) l_part[pp] = s_l[0] + s_l[1] + s_l[2] + s_l[3];
  }
}

// ---------------- k2: combine partials -> normalized context ----------------
__global__ __launch_bounds__(128) void k2_combine(
    const float* __restrict__ ctx_part, const float* __restrict__ l_part,
    float* __restrict__ ctx)
{
  const int b = blockIdx.x;
  const int h = threadIdx.x * 4;
  float L = 0.f;
  for (int p = 0; p < NCHUNK; ++p) L += l_part[b*NCHUNK + p];
  float4 a = make_float4(0.f,0.f,0.f,0.f);
  for (int p = 0; p < NCHUNK; ++p) {
    const float4 v = *(const float4*)(ctx_part + ((size_t)b*NCHUNK + p)*HH + h);
    a.x += v.x; a.y += v.y; a.z += v.z; a.w += v.w;
  }
  const float inv = 1.f / L;
  *(float4*)(ctx + b*HH + h) = make_float4(a.x*inv, a.y*inv, a.z*inv, a.w*inv);
}

// ---------------- k3: out_part = ctx @ out_w^T over h-quarters --------------
// thread-per-c, 256-thread blocks, grid (125, 4): ~8 waves/CU for latency
// hiding on the 64MB out_w stream. ctx reads are wave-uniform -> L1 broadcast.
__global__ __launch_bounds__(256) void k3_matmul(
    const float* __restrict__ ctx, const float* __restrict__ ow,
    float* __restrict__ out_part)
{
  const int c = blockIdx.x * 256 + threadIdx.x;
  const int q = blockIdx.y;               // h in [q*128, q*128+128)
  const int h0 = q * 128;
  const float* wrow = ow + (size_t)c * HH + h0;
  const float* cb = ctx + h0;             // uniform across block
  float acc[BB];
  #pragma unroll
  for (int b = 0; b < BB; ++b) acc[b] = 0.f;
  #pragma unroll 4
  for (int hh = 0; hh < 128; hh += 4) {
    const float4 w4 = *(const float4*)(wrow + hh);
    #pragma unroll
    for (int b = 0; b < BB; ++b) {
      const float4 c4 = *(const float4*)(cb + (size_t)b*HH + hh);
      acc[b] = fmaf(w4.w, c4.w, fmaf(w4.z, c4.z, fmaf(w4.y, c4.y, fmaf(w4.x, c4.x, acc[b]))));
    }
  }
  float* op = out_part + (size_t)q * ((size_t)BB*CC);
  #pragma unroll
  for (int b = 0; b < BB; ++b) op[(size_t)b*CC + c] = acc[b];
}

// ---------------- k4: sum quarters + bias -> d_out --------------------------
__global__ __launch_bounds__(256) void k4_final(
    const float* __restrict__ out_part, const float* __restrict__ ob,
    float* __restrict__ out)
{
  const size_t i = ((size_t)blockIdx.x * 256 + threadIdx.x) * 4;
  float4 r = *(const float4*)(out_part + i);
  #pragma unroll
  for (int q = 1; q < NQ; ++q) {
    const float4 p = *(const float4*)(out_part + (size_t)q*((size_t)BB*CC) + i);
    r.x += p.x; r.y += p.y; r.z += p.z; r.w += p.w;
  }
  const int cIdx = (int)(i % CC);
  const float4 b4 = *(const float4*)(ob + cIdx);
  *(float4*)(out + i) = make_float4(r.x+b4.x, r.y+b4.y, r.z+b4.z, r.w+b4.w);
}

extern "C" void kernel_launch(void* const* d_in, const int* in_sizes, int n_in,
                              void* d_out, int out_size, void* d_ws, size_t ws_size,
                              hipStream_t stream) {
  const float* dec = (const float*)d_in[0];
  const float* aw  = (const float*)d_in[1];
  const float* ab  = (const float*)d_in[2];
  const float* ow  = (const float*)d_in[3];
  const float* ob  = (const float*)d_in[4];
  float* out = (float*)d_out;
  float* ws  = (float*)d_ws;
  float* ctx   = ws + WS_CTX;
  float* lpart = ws + WS_LPART;
  float* big   = ws + WS_BIG;   // ctx_part for k1/k2, reused as out_part for k3/k4

  k1_partials<<<dim3(NCHUNK, BB), 256, 0, stream>>>(dec, aw, ab, big, lpart);
  k2_combine<<<dim3(BB), 128, 0, stream>>>(big, lpart, ctx);
  k3_matmul<<<dim3(CC/256, NQ), 256, 0, stream>>>(ctx, ow, big);
  k4_final<<<dim3((BB*CC)/(256*4)), 256, 0, stream>>>(big, ob, out);
}